// Round 1
// baseline (1238.770 us; speedup 1.0000x reference)
//
#include <hip/hip_runtime.h>
#include <stdint.h>
#include <math.h>

// Problem constants
constexpr int Bb = 8, Tt = 512, Hh = 2048, Vv = 32000;
constexpr int M = Bb * Tt;     // 4096 tokens
constexpr int K = Hh;          // 2048
constexpr int N = Vv;          // 32000 vocab
constexpr int NB = N / 128;    // 250 column blocks
constexpr int IGNORE = -100;

typedef __attribute__((ext_vector_type(8))) short bf16x8;
typedef __attribute__((ext_vector_type(4))) float f32x4;

__device__ inline void gld16(const void* g, const void* l) {
  __builtin_amdgcn_global_load_lds(
      (const __attribute__((address_space(1))) uint32_t*)g,
      (__attribute__((address_space(3))) uint32_t*)l, 16, 0, 0);
}

__device__ inline unsigned short f2bf(float f) {
  union { float f; unsigned u; } x; x.f = f;
  unsigned r = x.u + 0x7fffu + ((x.u >> 16) & 1u);  // RNE
  return (unsigned short)(r >> 16);
}

// ---------------- cast fp32 -> bf16, vectorized ----------------
__global__ void cast_bf16_kernel(const float* __restrict__ src,
                                 unsigned short* __restrict__ dst, int n4) {
  int i = blockIdx.x * blockDim.x + threadIdx.x;
  int stride = gridDim.x * blockDim.x;
  const float4* s4 = (const float4*)src;
  ushort4* d4 = (ushort4*)dst;
  for (; i < n4; i += stride) {
    float4 v = s4[i];
    ushort4 o;
    o.x = f2bf(v.x); o.y = f2bf(v.y); o.z = f2bf(v.z); o.w = f2bf(v.w);
    d4[i] = o;
  }
}

// ---------------- GEMM + fused per-row softmax-stats epilogue ----------------
// C[m][n] = sum_k X[m][k]*W[n][k] + bias[n]; per 128x128 tile emit per-row
// partial (max, sumexp) and scatter logit where n == target[m].
__global__ __launch_bounds__(256)
void gemm_stats(const unsigned short* __restrict__ X,
                const unsigned short* __restrict__ W,
                const float* __restrict__ bias,
                const int* __restrict__ tgt,
                float* __restrict__ m_part,
                float* __restrict__ s_part,
                float* __restrict__ tlogit) {
  __shared__ __align__(16) unsigned short As[128 * 64];
  __shared__ __align__(16) unsigned short Bs[128 * 64];
  __shared__ float red_m[2][128];
  __shared__ float red_s[2][128];

  const int tid = threadIdx.x;
  const int lane = tid & 63;
  const int wid = tid >> 6;          // 4 waves
  const int waveM = wid >> 1;        // 2x2 wave grid, each wave 64x64
  const int waveN = wid & 1;
  const int q = lane >> 4;           // quad 0..3
  const int c = lane & 15;
  const int bm = blockIdx.x;         // 0..31  (m fastest -> weight streams ~once)
  const int bn = blockIdx.y;         // 0..249

  // staging: each wave loads 32 rows of A-tile and 32 rows of B-tile
  const int srow = lane >> 3;                 // 0..7 within an 8-row chunk
  const int scol = (lane & 7) * 8;            // 8 bf16 = 16 B
  const unsigned short* gA = X + (size_t)(bm * 128 + wid * 32 + srow) * K + scol;
  const unsigned short* gB = W + (size_t)(bn * 128 + wid * 32 + srow) * K + scol;

  f32x4 acc[4][4];
#pragma unroll
  for (int i = 0; i < 4; ++i)
#pragma unroll
    for (int j = 0; j < 4; ++j) acc[i][j] = (f32x4){0.f, 0.f, 0.f, 0.f};

  for (int k0 = 0; k0 < K; k0 += 64) {
#pragma unroll
    for (int j = 0; j < 4; ++j) {
      gld16(gA + (size_t)j * 8 * K + k0, As + (wid * 32 + j * 8) * 64);
      gld16(gB + (size_t)j * 8 * K + k0, Bs + (wid * 32 + j * 8) * 64);
    }
    __syncthreads();  // drains vmcnt -> LDS tiles visible
#pragma unroll
    for (int kk = 0; kk < 2; ++kk) {
      bf16x8 af[4], bfr[4];
#pragma unroll
      for (int i = 0; i < 4; ++i) {
        af[i]  = *(const bf16x8*)(As + (waveM * 64 + i * 16 + c) * 64 + kk * 32 + q * 8);
        bfr[i] = *(const bf16x8*)(Bs + (waveN * 64 + i * 16 + c) * 64 + kk * 32 + q * 8);
      }
#pragma unroll
      for (int mi = 0; mi < 4; ++mi)
#pragma unroll
        for (int ni = 0; ni < 4; ++ni)
          acc[mi][ni] = __builtin_amdgcn_mfma_f32_16x16x32_bf16(
              af[mi], bfr[ni], acc[mi][ni], 0, 0, 0);
    }
    __syncthreads();  // protect LDS from next iteration's staging
  }

  // ---- epilogue: per-row (max, sumexp) over this block's 128 columns ----
  const int colBase = bn * 128 + waveN * 64;
  float bvals[4];
#pragma unroll
  for (int ni = 0; ni < 4; ++ni) bvals[ni] = bias[colBase + ni * 16 + c];

#pragma unroll
  for (int mi = 0; mi < 4; ++mi) {
    const int rowBase = bm * 128 + waveM * 64 + mi * 16 + q * 4;
#pragma unroll
    for (int reg = 0; reg < 4; ++reg) {
      const int grow = rowBase + reg;
      const int t = tgt[grow];
      float v[4];
      float mloc = -3.4e38f;
#pragma unroll
      for (int ni = 0; ni < 4; ++ni) {
        v[ni] = acc[mi][ni][reg] + bvals[ni];
        mloc = fmaxf(mloc, v[ni]);
        const int gn = colBase + ni * 16 + c;
        if (gn == t) tlogit[grow] = v[ni];  // exactly one lane/block matches
      }
#pragma unroll
      for (int off = 1; off < 16; off <<= 1) mloc = fmaxf(mloc, __shfl_xor(mloc, off));
      float sloc = 0.f;
#pragma unroll
      for (int ni = 0; ni < 4; ++ni) sloc += __expf(v[ni] - mloc);
#pragma unroll
      for (int off = 1; off < 16; off <<= 1) sloc += __shfl_xor(sloc, off);
      if (c == 0) {
        const int lrow = waveM * 64 + mi * 16 + q * 4 + reg;
        red_m[waveN][lrow] = mloc;
        red_s[waveN][lrow] = sloc;
      }
    }
  }
  __syncthreads();
  if (tid < 128) {
    const float m0 = red_m[0][tid], m1 = red_m[1][tid];
    const float s0 = red_s[0][tid], s1 = red_s[1][tid];
    const float mx = fmaxf(m0, m1);
    const float ss = s0 * __expf(m0 - mx) + s1 * __expf(m1 - mx);
    const int grow = bm * 128 + tid;
    m_part[(size_t)grow * NB + bn] = mx;
    s_part[(size_t)grow * NB + bn] = ss;
  }
}

// ---------------- combine per-row partials -> per-token logp ----------------
__global__ __launch_bounds__(256)
void combine_rows(const float* __restrict__ m_part, const float* __restrict__ s_part,
                  const float* __restrict__ tlogit, const int* __restrict__ tgt,
                  float* __restrict__ logp) {
  const int row = blockIdx.x * 4 + (threadIdx.x >> 6);
  const int lane = threadIdx.x & 63;
  const float* mrow = m_part + (size_t)row * NB;
  const float* srow = s_part + (size_t)row * NB;
  float mv[4], sv[4];
  int cnt = 0;
  float mx = -3.4e38f;
  for (int cc = lane; cc < NB; cc += 64) {
    mv[cnt] = mrow[cc]; sv[cnt] = srow[cc];
    mx = fmaxf(mx, mv[cnt]); ++cnt;
  }
#pragma unroll
  for (int off = 32; off >= 1; off >>= 1) mx = fmaxf(mx, __shfl_xor(mx, off));
  float s = 0.f;
  for (int i = 0; i < cnt; ++i) s += sv[i] * __expf(mv[i] - mx);
#pragma unroll
  for (int off = 32; off >= 1; off >>= 1) s += __shfl_xor(s, off);
  if (lane == 0) {
    const int t = tgt[row];
    logp[row] = (t == IGNORE) ? 0.f : (tlogit[row] - mx - logf(s));
  }
}

// ---------------- per-sequence average + SimPO loss ----------------
__global__ void finalize(const float* __restrict__ logp, const int* __restrict__ tgt,
                         float* __restrict__ out) {
  __shared__ float avg[8];
  const int w = threadIdx.x >> 6;     // 8 waves, one per sequence
  const int lane = threadIdx.x & 63;
  float s = 0.f, cnt = 0.f;
  for (int i = lane; i < Tt; i += 64) {
    const int idx = w * Tt + i;
    s += logp[idx];
    cnt += (tgt[idx] != IGNORE) ? 1.f : 0.f;
  }
#pragma unroll
  for (int off = 32; off >= 1; off >>= 1) {
    s += __shfl_xor(s, off);
    cnt += __shfl_xor(cnt, off);
  }
  if (lane == 0) avg[w] = s / fmaxf(cnt, 1.f);
  __syncthreads();
  if (threadIdx.x == 0) {
    float loss = 0.f;
#pragma unroll
    for (int p = 0; p < 4; ++p) {
      const float d = 0.1f * (avg[p] - avg[p + 4]) - 0.5f;
      const float nl = (d > 0.f) ? log1pf(expf(-d)) : (-d + log1pf(expf(d)));
      loss += nl;
    }
    out[0] = loss * 0.25f;  // / n_pairs
  }
}

extern "C" void kernel_launch(void* const* d_in, const int* in_sizes, int n_in,
                              void* d_out, int out_size, void* d_ws, size_t ws_size,
                              hipStream_t stream) {
  const float* Wf   = (const float*)d_in[0];  // lin_weight (V,H)
  const float* Xf   = (const float*)d_in[1];  // _input (B,T,H)
  const int*   tgt  = (const int*)d_in[2];    // target (B,T)
  const float* bias = (const float*)d_in[3];  // bias (V,)
  float* out = (float*)d_out;

  char* ws = (char*)d_ws;
  size_t off = 0;
  auto alloc = [&](size_t bytes) {
    void* p = ws + off;
    off += (bytes + 255) & ~(size_t)255;
    return p;
  };
  unsigned short* Xbf = (unsigned short*)alloc((size_t)M * K * 2);
  unsigned short* Wbf = (unsigned short*)alloc((size_t)N * K * 2);
  float* m_part = (float*)alloc((size_t)M * NB * 4);
  float* s_part = (float*)alloc((size_t)M * NB * 4);
  float* tlog   = (float*)alloc((size_t)M * 4);
  float* logp   = (float*)alloc((size_t)M * 4);

  cast_bf16_kernel<<<2048, 256, 0, stream>>>(Xf, Xbf, M * K / 4);
  cast_bf16_kernel<<<8192, 256, 0, stream>>>(Wf, Wbf, N * K / 4);

  dim3 grid(M / 128, NB);  // 32 x 250; m fastest for weight-stream L2/L3 reuse
  gemm_stats<<<grid, 256, 0, stream>>>(Xbf, Wbf, bias, tgt, m_part, s_part, tlog);

  combine_rows<<<M / 4, 256, 0, stream>>>(m_part, s_part, tlog, tgt, logp);
  finalize<<<1, 512, 0, stream>>>(logp, tgt, out);
}

// Round 2
// 1062.961 us; speedup vs baseline: 1.1654x; 1.1654x over previous
//
#include <hip/hip_runtime.h>
#include <stdint.h>
#include <math.h>

// Problem constants
constexpr int Bb = 8, Tt = 512, Hh = 2048, Vv = 32000;
constexpr int M = Bb * Tt;     // 4096 tokens
constexpr int K = Hh;          // 2048
constexpr int N = Vv;          // 32000 vocab
constexpr int NB = N / 128;    // 250 column blocks
constexpr int IGNORE = -100;

typedef __attribute__((ext_vector_type(8))) short bf16x8;
typedef __attribute__((ext_vector_type(4))) float f32x4;

__device__ inline void gld16(const void* g, const void* l) {
  __builtin_amdgcn_global_load_lds(
      (const __attribute__((address_space(1))) uint32_t*)g,
      (__attribute__((address_space(3))) uint32_t*)l, 16, 0, 0);
}

__device__ inline unsigned short f2bf(float f) {
  union { float f; unsigned u; } x; x.f = f;
  unsigned r = x.u + 0x7fffu + ((x.u >> 16) & 1u);  // RNE
  return (unsigned short)(r >> 16);
}

// ---------------- cast fp32 -> bf16, vectorized ----------------
__global__ void cast_bf16_kernel(const float* __restrict__ src,
                                 unsigned short* __restrict__ dst, int n4) {
  int i = blockIdx.x * blockDim.x + threadIdx.x;
  int stride = gridDim.x * blockDim.x;
  const float4* s4 = (const float4*)src;
  ushort4* d4 = (ushort4*)dst;
  for (; i < n4; i += stride) {
    float4 v = s4[i];
    ushort4 o;
    o.x = f2bf(v.x); o.y = f2bf(v.y); o.z = f2bf(v.z); o.w = f2bf(v.w);
    d4[i] = o;
  }
}

// ---------------- GEMM + fused per-row softmax-stats epilogue ----------------
// C[m][n] = sum_k X[m][k]*W[n][k] + bias[n]; per 128x128 tile emit per-row
// partial (max, sumexp) and scatter logit where n == target[m].
//
// LDS layout is XOR-swizzled at 16B granularity: 16B-chunk j of row r is
// stored at chunk slot (j ^ (r&7)). Applied on the GLOBAL source address at
// staging time (global_load_lds forces lane->base+lane*16 on the LDS side);
// the swizzle permutes lanes within a 128B global segment -> still coalesced.
// Fragment reads XOR by (c&7): 16 lanes/quad -> 32 banks, 2 lanes/bank (free).
__global__ __launch_bounds__(256)
void gemm_stats(const unsigned short* __restrict__ X,
                const unsigned short* __restrict__ W,
                const float* __restrict__ bias,
                const int* __restrict__ tgt,
                float* __restrict__ m_part,
                float* __restrict__ s_part,
                float* __restrict__ tlogit) {
  __shared__ __align__(16) unsigned short As[128 * 64];
  __shared__ __align__(16) unsigned short Bs[128 * 64];
  __shared__ float red_m[2][128];
  __shared__ float red_s[2][128];

  const int tid = threadIdx.x;
  const int lane = tid & 63;
  const int wid = tid >> 6;          // 4 waves
  const int waveM = wid >> 1;        // 2x2 wave grid, each wave 64x64
  const int waveN = wid & 1;
  const int q = lane >> 4;           // quad 0..3
  const int c = lane & 15;
  const int bm = blockIdx.x;         // 0..31  (m fastest -> weight streams ~once)
  const int bn = blockIdx.y;         // 0..249

  // staging: each wave loads 32 rows of A-tile and 32 rows of B-tile.
  // LDS row for lane = wid*32 + j*8 + srow; key = srow (rows mod 8).
  const int srow = lane >> 3;                       // 0..7
  const int scol = ((lane & 7) ^ srow) * 8;         // swizzled 16B chunk
  const unsigned short* gA = X + (size_t)(bm * 128 + wid * 32 + srow) * K + scol;
  const unsigned short* gB = W + (size_t)(bn * 128 + wid * 32 + srow) * K + scol;

  f32x4 acc[4][4];
#pragma unroll
  for (int i = 0; i < 4; ++i)
#pragma unroll
    for (int j = 0; j < 4; ++j) acc[i][j] = (f32x4){0.f, 0.f, 0.f, 0.f};

  for (int k0 = 0; k0 < K; k0 += 64) {
#pragma unroll
    for (int j = 0; j < 4; ++j) {
      gld16(gA + (size_t)j * 8 * K + k0, As + (wid * 32 + j * 8) * 64);
      gld16(gB + (size_t)j * 8 * K + k0, Bs + (wid * 32 + j * 8) * 64);
    }
    __syncthreads();  // drains vmcnt -> LDS tiles visible
#pragma unroll
    for (int kk = 0; kk < 2; ++kk) {
      bf16x8 af[4], bfr[4];
#pragma unroll
      for (int i = 0; i < 4; ++i) {
        const int rA = waveM * 64 + i * 16 + c;
        const int rB = waveN * 64 + i * 16 + c;
        const int chunk = kk * 4 + q;
        af[i]  = *(const bf16x8*)(As + rA * 64 + ((chunk ^ (rA & 7)) * 8));
        bfr[i] = *(const bf16x8*)(Bs + rB * 64 + ((chunk ^ (rB & 7)) * 8));
      }
#pragma unroll
      for (int mi = 0; mi < 4; ++mi)
#pragma unroll
        for (int ni = 0; ni < 4; ++ni)
          acc[mi][ni] = __builtin_amdgcn_mfma_f32_16x16x32_bf16(
              af[mi], bfr[ni], acc[mi][ni], 0, 0, 0);
    }
    __syncthreads();  // protect LDS from next iteration's staging
  }

  // ---- epilogue: per-row (max, sumexp) over this block's 128 columns ----
  const int colBase = bn * 128 + waveN * 64;
  float bvals[4];
#pragma unroll
  for (int ni = 0; ni < 4; ++ni) bvals[ni] = bias[colBase + ni * 16 + c];

#pragma unroll
  for (int mi = 0; mi < 4; ++mi) {
    const int rowBase = bm * 128 + waveM * 64 + mi * 16 + q * 4;
#pragma unroll
    for (int reg = 0; reg < 4; ++reg) {
      const int grow = rowBase + reg;
      const int t = tgt[grow];
      float v[4];
      float mloc = -3.4e38f;
#pragma unroll
      for (int ni = 0; ni < 4; ++ni) {
        v[ni] = acc[mi][ni][reg] + bvals[ni];
        mloc = fmaxf(mloc, v[ni]);
        const int gn = colBase + ni * 16 + c;
        if (gn == t) tlogit[grow] = v[ni];  // exactly one lane/block matches
      }
#pragma unroll
      for (int off = 1; off < 16; off <<= 1) mloc = fmaxf(mloc, __shfl_xor(mloc, off));
      float sloc = 0.f;
#pragma unroll
      for (int ni = 0; ni < 4; ++ni) sloc += __expf(v[ni] - mloc);
#pragma unroll
      for (int off = 1; off < 16; off <<= 1) sloc += __shfl_xor(sloc, off);
      if (c == 0) {
        const int lrow = waveM * 64 + mi * 16 + q * 4 + reg;
        red_m[waveN][lrow] = mloc;
        red_s[waveN][lrow] = sloc;
      }
    }
  }
  __syncthreads();
  if (tid < 128) {
    const float m0 = red_m[0][tid], m1 = red_m[1][tid];
    const float s0 = red_s[0][tid], s1 = red_s[1][tid];
    const float mx = fmaxf(m0, m1);
    const float ss = s0 * __expf(m0 - mx) + s1 * __expf(m1 - mx);
    const int grow = bm * 128 + tid;
    m_part[(size_t)grow * NB + bn] = mx;
    s_part[(size_t)grow * NB + bn] = ss;
  }
}

// ---------------- combine per-row partials -> per-token logp ----------------
__global__ __launch_bounds__(256)
void combine_rows(const float* __restrict__ m_part, const float* __restrict__ s_part,
                  const float* __restrict__ tlogit, const int* __restrict__ tgt,
                  float* __restrict__ logp) {
  const int row = blockIdx.x * 4 + (threadIdx.x >> 6);
  const int lane = threadIdx.x & 63;
  const float* mrow = m_part + (size_t)row * NB;
  const float* srow = s_part + (size_t)row * NB;
  float mv[4], sv[4];
  int cnt = 0;
  float mx = -3.4e38f;
  for (int cc = lane; cc < NB; cc += 64) {
    mv[cnt] = mrow[cc]; sv[cnt] = srow[cc];
    mx = fmaxf(mx, mv[cnt]); ++cnt;
  }
#pragma unroll
  for (int off = 32; off >= 1; off >>= 1) mx = fmaxf(mx, __shfl_xor(mx, off));
  float s = 0.f;
  for (int i = 0; i < cnt; ++i) s += sv[i] * __expf(mv[i] - mx);
#pragma unroll
  for (int off = 32; off >= 1; off >>= 1) s += __shfl_xor(s, off);
  if (lane == 0) {
    const int t = tgt[row];
    logp[row] = (t == IGNORE) ? 0.f : (tlogit[row] - mx - logf(s));
  }
}

// ---------------- per-sequence average + SimPO loss ----------------
__global__ void finalize(const float* __restrict__ logp, const int* __restrict__ tgt,
                         float* __restrict__ out) {
  __shared__ float avg[8];
  const int w = threadIdx.x >> 6;     // 8 waves, one per sequence
  const int lane = threadIdx.x & 63;
  float s = 0.f, cnt = 0.f;
  for (int i = lane; i < Tt; i += 64) {
    const int idx = w * Tt + i;
    s += logp[idx];
    cnt += (tgt[idx] != IGNORE) ? 1.f : 0.f;
  }
#pragma unroll
  for (int off = 32; off >= 1; off >>= 1) {
    s += __shfl_xor(s, off);
    cnt += __shfl_xor(cnt, off);
  }
  if (lane == 0) avg[w] = s / fmaxf(cnt, 1.f);
  __syncthreads();
  if (threadIdx.x == 0) {
    float loss = 0.f;
#pragma unroll
    for (int p = 0; p < 4; ++p) {
      const float d = 0.1f * (avg[p] - avg[p + 4]) - 0.5f;
      const float nl = (d > 0.f) ? log1pf(expf(-d)) : (-d + log1pf(expf(d)));
      loss += nl;
    }
    out[0] = loss * 0.25f;  // / n_pairs
  }
}

extern "C" void kernel_launch(void* const* d_in, const int* in_sizes, int n_in,
                              void* d_out, int out_size, void* d_ws, size_t ws_size,
                              hipStream_t stream) {
  const float* Wf   = (const float*)d_in[0];  // lin_weight (V,H)
  const float* Xf   = (const float*)d_in[1];  // _input (B,T,H)
  const int*   tgt  = (const int*)d_in[2];    // target (B,T)
  const float* bias = (const float*)d_in[3];  // bias (V,)
  float* out = (float*)d_out;

  char* ws = (char*)d_ws;
  size_t off = 0;
  auto alloc = [&](size_t bytes) {
    void* p = ws + off;
    off += (bytes + 255) & ~(size_t)255;
    return p;
  };
  unsigned short* Xbf = (unsigned short*)alloc((size_t)M * K * 2);
  unsigned short* Wbf = (unsigned short*)alloc((size_t)N * K * 2);
  float* m_part = (float*)alloc((size_t)M * NB * 4);
  float* s_part = (float*)alloc((size_t)M * NB * 4);
  float* tlog   = (float*)alloc((size_t)M * 4);
  float* logp   = (float*)alloc((size_t)M * 4);

  cast_bf16_kernel<<<2048, 256, 0, stream>>>(Xf, Xbf, M * K / 4);
  cast_bf16_kernel<<<8192, 256, 0, stream>>>(Wf, Wbf, N * K / 4);

  dim3 grid(M / 128, NB);  // 32 x 250; m fastest for weight-stream L2/L3 reuse
  gemm_stats<<<grid, 256, 0, stream>>>(Xbf, Wbf, bias, tgt, m_part, s_part, tlog);

  combine_rows<<<M / 4, 256, 0, stream>>>(m_part, s_part, tlog, tgt, logp);
  finalize<<<1, 512, 0, stream>>>(logp, tgt, out);
}